// Round 4
// baseline (350.882 us; speedup 1.0000x reference)
//
#include <hip/hip_runtime.h>
#include <cstddef>
#include <stdint.h>

#define HYP_C   0.1f
#define SQRT_C  0.31622776601683794f
#define CLIP_R  2.3f
#define MRG     0.1f
#define NPROX   256
#define DIM     128

// workspace layout (float offsets)
#define OFF_LH   0         // lh row-major      [256][128]
#define OFF_LHT  32768     // lh transposed     [128][256]
#define OFF_LN2  65536     // ||lh_m||^2        [256]
#define OFF_D1   65792     // dist(z, lh)       [1024][256]
#define OFF_D2   327936    // dist(lh, lh)      [256][256]
#define OFF_D3   393472    // dist(t, lh)       [1024][256]

// ---------------------------------------------------------------------------
// Kernel A: to_poincare(lcas) -> lh, lhT, ln2 ; also zero d_out
// ---------------------------------------------------------------------------
__global__ __launch_bounds__(128)
void to_poincare_kernel(const float* __restrict__ lcas,
                        float* __restrict__ ws,
                        float* __restrict__ out)
{
    const int row = blockIdx.x;
    const int k   = threadIdx.x;
    if (row == 0 && k == 0) out[0] = 0.0f;

    float v  = lcas[row * DIM + k];
    float ss = v * v;
    #pragma unroll
    for (int off = 32; off >= 1; off >>= 1)
        ss += __shfl_xor(ss, off, 64);
    __shared__ float wpart[2];
    if ((k & 63) == 0) wpart[k >> 6] = ss;
    __syncthreads();
    const float sumsq = wpart[0] + wpart[1];

    const float s1 = sqrtf(sumsq);
    const float xn = s1 + 1e-5f;
    const float f1 = fminf(1.0f, CLIP_R / xn);
    const float xn2 = fmaxf(f1 * s1, 1e-5f);
    const float th  = tanhf(SQRT_C * xn2);
    const float f2  = th / (SQRT_C * xn2);
    const float nr      = fmaxf(f2 * f1 * s1, 1e-5f);
    const float maxnorm = (1.0f - 1e-3f) / SQRT_C;
    const float f3      = (nr > maxnorm) ? (maxnorm / nr) : 1.0f;

    const float f  = f3 * f2 * f1;
    const float lv = f * v;
    ws[OFF_LH  + row * DIM + k]   = lv;
    ws[OFF_LHT + k * NPROX + row] = lv;
    if (k == 0) ws[OFF_LN2 + row] = f * f * sumsq;
}

// ---------------------------------------------------------------------------
// Kernel B: all three distance matrices in one launch. 4 rows/block.
// ---------------------------------------------------------------------------
__global__ __launch_bounds__(256)
void dist_all_kernel(const float* __restrict__ z,
                     const float* __restrict__ t,
                     float* __restrict__ ws, int nb1)
{
    const float* lhT = ws + OFF_LHT;
    const float* ln2 = ws + OFF_LN2;

    int b = blockIdx.x;
    const float* X; float* Dout; int row0;
    if (b < nb1)            { X = z;            Dout = ws + OFF_D1; row0 = b * 4; }
    else if (b < nb1 + 64)  { X = ws + OFF_LH;  Dout = ws + OFF_D2; row0 = (b - nb1) * 4; }
    else                    { X = t;            Dout = ws + OFF_D3; row0 = (b - nb1 - 64) * 4; }

    __shared__ float xs[4][DIM];
    __shared__ float sx2[4];

    for (int idx = threadIdx.x; idx < 4 * DIM; idx += 256)
        xs[idx / DIM][idx % DIM] = X[row0 * DIM + idx];
    __syncthreads();

    const int wid  = threadIdx.x >> 6;
    const int lane = threadIdx.x & 63;
    {
        float a = xs[wid][lane];
        float c = xs[wid][lane + 64];
        float s = a * a + c * c;
        #pragma unroll
        for (int off = 32; off >= 1; off >>= 1)
            s += __shfl_xor(s, off, 64);
        if (lane == 0) sx2[wid] = s;
    }
    __syncthreads();

    const int m = threadIdx.x;
    float dot0 = 0.f, dot1 = 0.f, dot2 = 0.f, dot3 = 0.f;
    #pragma unroll 8
    for (int k = 0; k < DIM; k += 4) {
        const float4 x0 = *(const float4*)&xs[0][k];
        const float4 x1 = *(const float4*)&xs[1][k];
        const float4 x2 = *(const float4*)&xs[2][k];
        const float4 x3 = *(const float4*)&xs[3][k];
        const float l0 = lhT[(k + 0) * NPROX + m];
        const float l1 = lhT[(k + 1) * NPROX + m];
        const float l2 = lhT[(k + 2) * NPROX + m];
        const float l3 = lhT[(k + 3) * NPROX + m];
        dot0 = fmaf(x0.x, l0, fmaf(x0.y, l1, fmaf(x0.z, l2, fmaf(x0.w, l3, dot0))));
        dot1 = fmaf(x1.x, l0, fmaf(x1.y, l1, fmaf(x1.z, l2, fmaf(x1.w, l3, dot1))));
        dot2 = fmaf(x2.x, l0, fmaf(x2.y, l1, fmaf(x2.z, l2, fmaf(x2.w, l3, dot2))));
        dot3 = fmaf(x3.x, l0, fmaf(x3.y, l1, fmaf(x3.z, l2, fmaf(x3.w, l3, dot3))));
    }

    const float y2 = ln2[m];
    float dots[4] = {dot0, dot1, dot2, dot3};
    #pragma unroll
    for (int r = 0; r < 4; ++r) {
        const float x2 = sx2[r];
        const float xy = -dots[r];
        const float a  = 1.0f + 2.0f * HYP_C * xy + HYP_C * y2;
        const float bb = 1.0f - HYP_C * x2;
        const float denom  = 1.0f + 2.0f * HYP_C * xy + HYP_C * HYP_C * x2 * y2;
        const float num_sq = a * a * x2 + 2.0f * a * bb * xy + bb * bb * y2;
        const float nrm = sqrtf(fmaxf(num_sq, 1e-12f)) / fabsf(denom + 1e-5f);
        float u = SQRT_C * nrm;
        u = fminf(fmaxf(u, -1.0f + 1e-5f), 1.0f - 1e-5f);
        const float d = (2.0f / SQRT_C) * (0.5f * (log1pf(u) - log1pf(-u)));
        Dout[(size_t)(row0 + r) * NPROX + m] = d;
    }
}

// ---------------------------------------------------------------------------
// Kernel C: fused ghhc, DPP edition.
// 16 lanes per triplet (16 elems/lane, strided: lane hl owns elems
// {m*64 + hl*4 + c}), 4 triplets per wave, 1 wave per block.
// Cross-lane argmax entirely via DPP row_ror (VALU speed, zero DS ops):
//   stage 1: rotate-reduce fmax over the 16-lane row  -> group max value gv
//   stage 2: rotate-reduce imax over (lv==gv ? 255-idx : 0) -> first index
// ---------------------------------------------------------------------------
__device__ __forceinline__ float dpp_fmax16(float x) {
    int o;
    o = __builtin_amdgcn_update_dpp(0, __float_as_int(x), 0x121, 0xF, 0xF, true);
    x = fmaxf(x, __int_as_float(o));
    o = __builtin_amdgcn_update_dpp(0, __float_as_int(x), 0x122, 0xF, 0xF, true);
    x = fmaxf(x, __int_as_float(o));
    o = __builtin_amdgcn_update_dpp(0, __float_as_int(x), 0x124, 0xF, 0xF, true);
    x = fmaxf(x, __int_as_float(o));
    o = __builtin_amdgcn_update_dpp(0, __float_as_int(x), 0x128, 0xF, 0xF, true);
    x = fmaxf(x, __int_as_float(o));
    return x;
}

__device__ __forceinline__ int dpp_imax16(int x) {
    int o;
    o = __builtin_amdgcn_update_dpp(0, x, 0x121, 0xF, 0xF, true); x = max(x, o);
    o = __builtin_amdgcn_update_dpp(0, x, 0x122, 0xF, 0xF, true); x = max(x, o);
    o = __builtin_amdgcn_update_dpp(0, x, 0x124, 0xF, 0xF, true); x = max(x, o);
    o = __builtin_amdgcn_update_dpp(0, x, 0x128, 0xF, 0xF, true); x = max(x, o);
    return x;
}

__device__ __forceinline__ void amax4(float v0, float v1, float v2, float v3,
                                      int base, float& lv, int& li)
{
    if (v0 > lv) { lv = v0; li = base; }
    if (v1 > lv) { lv = v1; li = base + 1; }
    if (v2 > lv) { lv = v2; li = base + 2; }
    if (v3 > lv) { lv = v3; li = base + 3; }
}

__global__ __launch_bounds__(64, 4)
void ghhc_fused_kernel(const float* __restrict__ Da, const float* __restrict__ Db,
                       const float* __restrict__ Dc, const float* __restrict__ Dd,
                       const int* __restrict__ ta, const int* __restrict__ tb,
                       const int* __restrict__ tc, const int* __restrict__ td,
                       const float* __restrict__ ga, const float* __restrict__ gb,
                       const float* __restrict__ gc, const float* __restrict__ gd,
                       int Ta, int Tb, int Tc, int Td,
                       float sa, float sb, float sc_, float sd,
                       int nba, int nbb, int nbc,
                       float* __restrict__ out)
{
    const int lane = threadIdx.x;     // 0..63
    const int grp  = lane >> 4;       // 0..3 (triplet within wave)
    const int hl   = lane & 15;       // lane within 16-group

    const int b = blockIdx.x;
    const float* D; const int* tr; const float* g; int Tt; float sc; int lb;
    if (b < nba)                   { D = Da; tr = ta; g = ga; Tt = Ta; sc = sa;  lb = b; }
    else if (b < nba + nbb)        { D = Db; tr = tb; g = gb; Tt = Tb; sc = sb;  lb = b - nba; }
    else if (b < nba + nbb + nbc)  { D = Dc; tr = tc; g = gc; Tt = Tc; sc = sc_; lb = b - nba - nbb; }
    else                           { D = Dd; tr = td; g = gd; Tt = Td; sc = sd;  lb = b - nba - nbb - nbc; }

    const int tstart = lb * 32;
    float acc = 0.0f;

    #pragma unroll 2
    for (int it = 0; it < 8; ++it) {
        const int tt = tstart + it * 4 + grp;
        const bool ok = tt < Tt;
        const int ts = ok ? tt : (Tt - 1);
        const int i = tr[ts], j = tr[Tt + ts], kk = tr[2 * Tt + ts];

        const float4* Di = (const float4*)(D + (size_t)i  * NPROX);
        const float4* Dj = (const float4*)(D + (size_t)j  * NPROX);
        const float4* Dk = (const float4*)(D + (size_t)kk * NPROX);
        const float4* G0 = (const float4*)(g + (size_t)ts * NPROX);
        const float4* G1 = (const float4*)(g + ((size_t)Tt + ts) * NPROX);

        float lvA = -__builtin_inff(), lvB = -__builtin_inff();
        int   liA = 0, liB = 0;

        #pragma unroll
        for (int m = 0; m < 4; ++m) {
            const int q = m * 16 + hl;
            const float4 di = Di[q], dj = Dj[q], dk = Dk[q];
            const float4 g0 = G0[q], g1 = G1[q];

            const float m1x = fmaxf(di.x, dj.x), m1y = fmaxf(di.y, dj.y),
                        m1z = fmaxf(di.z, dj.z), m1w = fmaxf(di.w, dj.w);
            const float sx = fmaf(m1x, -10.0f, g0.x), sy = fmaf(m1y, -10.0f, g0.y),
                        sz = fmaf(m1z, -10.0f, g0.z), sw = fmaf(m1w, -10.0f, g0.w);
            const float m2x = fmaxf(dk.x, m1x), m2y = fmaxf(dk.y, m1y),
                        m2z = fmaxf(dk.z, m1z), m2w = fmaxf(dk.w, m1w);
            const float ux = fmaf(m2x, -10.0f, g1.x), uy = fmaf(m2y, -10.0f, g1.y),
                        uz = fmaf(m2z, -10.0f, g1.z), uw = fmaf(m2w, -10.0f, g1.w);

            const int base = m * 64 + hl * 4;
            amax4(sx, sy, sz, sw, base, lvA, liA);
            amax4(ux, uy, uz, uw, base, lvB, liB);
        }

        const float gvA = dpp_fmax16(lvA);
        const int   A   = 255 - dpp_imax16((lvA == gvA) ? (255 - liA) : 0);
        const float gvB = dpp_fmax16(lvB);
        const int   B   = 255 - dpp_imax16((lvB == gvB) ? (255 - liB) : 0);

        // epilogue reloads: uniform address per 16-group -> broadcast lines
        const float diA = D[(size_t)i  * NPROX + A], diB = D[(size_t)i  * NPROX + B];
        const float djA = D[(size_t)j  * NPROX + A], djB = D[(size_t)j  * NPROX + B];
        const float dkA = D[(size_t)kk * NPROX + A], dkB = D[(size_t)kk * NPROX + B];
        const float hc = fmaxf(diA - diB + MRG, 0.0f)
                       + fmaxf(djA - djB + MRG, 0.0f)
                       + fmaxf(dkB - dkA + MRG, 0.0f);
        acc += (ok && (A != B) && (hl == 0)) ? hc * sc : 0.0f;
    }

    // wave sum (only hl==0 lanes carry nonzero)
    #pragma unroll
    for (int off = 32; off >= 1; off >>= 1)
        acc += __shfl_xor(acc, off, 64);
    if (lane == 0)
        atomicAdd(out, acc);
}

// ---------------------------------------------------------------------------
extern "C" void kernel_launch(void* const* d_in, const int* in_sizes, int n_in,
                              void* d_out, int out_size, void* d_ws, size_t ws_size,
                              hipStream_t stream)
{
    const float* z_s  = (const float*)d_in[0];
    const float* t_s  = (const float*)d_in[1];
    const float* lcas = (const float*)d_in[3];
    const int* trip1 = (const int*)d_in[4];
    const int* trip2 = (const int*)d_in[5];
    const int* trip3 = (const int*)d_in[6];
    const int* trip4 = (const int*)d_in[7];
    const float* g1 = (const float*)d_in[8];
    const float* g2 = (const float*)d_in[9];
    const float* g3 = (const float*)d_in[10];
    const float* g4 = (const float*)d_in[11];
    float* out = (float*)d_out;
    float* ws  = (float*)d_ws;

    const int T1 = in_sizes[4] / 3;   // 51200
    const int T2 = in_sizes[5] / 3;   // 12800
    const int T3 = in_sizes[6] / 3;   // 51200
    const int T4 = in_sizes[7] / 3;   // 12800
    const int BS = in_sizes[0] / DIM; // 1024
    const int nb1 = BS / 4;

    to_poincare_kernel<<<NPROX, 128, 0, stream>>>(lcas, ws, out);

    dist_all_kernel<<<2 * nb1 + 64, 256, 0, stream>>>(z_s, t_s, ws, nb1);

    // 32 triplets per block (1 wave, 4 triplets/iter, 8 iters)
    const int nbA = (T1 + 31) / 32;   // 1600
    const int nbB = (T2 + 31) / 32;   // 400
    const int nbC = (T3 + 31) / 32;   // 1600
    const int nbD = (T4 + 31) / 32;   // 400
    ghhc_fused_kernel<<<nbA + nbB + nbC + nbD, 64, 0, stream>>>(
        ws + OFF_D1, ws + OFF_D2, ws + OFF_D3, ws + OFF_D2,
        trip1, trip2, trip3, trip4,
        g1, g2, g3, g4,
        T1, T2, T3, T4,
        1.0f / (float)T1, 1.0f / (float)T2, 1.0f / (float)T3, 1.0f / (float)T4,
        nbA, nbB, nbC,
        out);
}

// Round 5
// 300.916 us; speedup vs baseline: 1.1660x; 1.1660x over previous
//
#include <hip/hip_runtime.h>
#include <cstddef>
#include <stdint.h>

#define HYP_C   0.1f
#define SQRT_C  0.31622776601683794f
#define CLIP_R  2.3f
#define MRG     0.1f
#define NPROX   256
#define DIM     128

// workspace layout (float offsets)
#define OFF_LH   0         // lh row-major      [256][128]
#define OFF_LHT  32768     // lh transposed     [128][256]
#define OFF_LN2  65536     // ||lh_m||^2        [256]
#define OFF_D1   65792     // dist(z, lh)       [1024][256]
#define OFF_D2   327936    // dist(lh, lh)      [256][256]
#define OFF_D3   393472    // dist(t, lh)       [1024][256]

// ---------------------------------------------------------------------------
// Kernel A: to_poincare(lcas) -> lh, lhT, ln2 ; also zero d_out
// ---------------------------------------------------------------------------
__global__ __launch_bounds__(128)
void to_poincare_kernel(const float* __restrict__ lcas,
                        float* __restrict__ ws,
                        float* __restrict__ out)
{
    const int row = blockIdx.x;
    const int k   = threadIdx.x;
    if (row == 0 && k == 0) out[0] = 0.0f;

    float v  = lcas[row * DIM + k];
    float ss = v * v;
    #pragma unroll
    for (int off = 32; off >= 1; off >>= 1)
        ss += __shfl_xor(ss, off, 64);
    __shared__ float wpart[2];
    if ((k & 63) == 0) wpart[k >> 6] = ss;
    __syncthreads();
    const float sumsq = wpart[0] + wpart[1];

    const float s1 = sqrtf(sumsq);
    const float xn = s1 + 1e-5f;
    const float f1 = fminf(1.0f, CLIP_R / xn);
    const float xn2 = fmaxf(f1 * s1, 1e-5f);
    const float th  = tanhf(SQRT_C * xn2);
    const float f2  = th / (SQRT_C * xn2);
    const float nr      = fmaxf(f2 * f1 * s1, 1e-5f);
    const float maxnorm = (1.0f - 1e-3f) / SQRT_C;
    const float f3      = (nr > maxnorm) ? (maxnorm / nr) : 1.0f;

    const float f  = f3 * f2 * f1;
    const float lv = f * v;
    ws[OFF_LH  + row * DIM + k]   = lv;
    ws[OFF_LHT + k * NPROX + row] = lv;
    if (k == 0) ws[OFF_LN2 + row] = f * f * sumsq;
}

// ---------------------------------------------------------------------------
// Kernel B: all three distance matrices in one launch. 4 rows/block.
// ---------------------------------------------------------------------------
__global__ __launch_bounds__(256)
void dist_all_kernel(const float* __restrict__ z,
                     const float* __restrict__ t,
                     float* __restrict__ ws, int nb1)
{
    const float* lhT = ws + OFF_LHT;
    const float* ln2 = ws + OFF_LN2;

    int b = blockIdx.x;
    const float* X; float* Dout; int row0;
    if (b < nb1)            { X = z;            Dout = ws + OFF_D1; row0 = b * 4; }
    else if (b < nb1 + 64)  { X = ws + OFF_LH;  Dout = ws + OFF_D2; row0 = (b - nb1) * 4; }
    else                    { X = t;            Dout = ws + OFF_D3; row0 = (b - nb1 - 64) * 4; }

    __shared__ float xs[4][DIM];
    __shared__ float sx2[4];

    for (int idx = threadIdx.x; idx < 4 * DIM; idx += 256)
        xs[idx / DIM][idx % DIM] = X[row0 * DIM + idx];
    __syncthreads();

    const int wid  = threadIdx.x >> 6;
    const int lane = threadIdx.x & 63;
    {
        float a = xs[wid][lane];
        float c = xs[wid][lane + 64];
        float s = a * a + c * c;
        #pragma unroll
        for (int off = 32; off >= 1; off >>= 1)
            s += __shfl_xor(s, off, 64);
        if (lane == 0) sx2[wid] = s;
    }
    __syncthreads();

    const int m = threadIdx.x;
    float dot0 = 0.f, dot1 = 0.f, dot2 = 0.f, dot3 = 0.f;
    #pragma unroll 8
    for (int k = 0; k < DIM; k += 4) {
        const float4 x0 = *(const float4*)&xs[0][k];
        const float4 x1 = *(const float4*)&xs[1][k];
        const float4 x2 = *(const float4*)&xs[2][k];
        const float4 x3 = *(const float4*)&xs[3][k];
        const float l0 = lhT[(k + 0) * NPROX + m];
        const float l1 = lhT[(k + 1) * NPROX + m];
        const float l2 = lhT[(k + 2) * NPROX + m];
        const float l3 = lhT[(k + 3) * NPROX + m];
        dot0 = fmaf(x0.x, l0, fmaf(x0.y, l1, fmaf(x0.z, l2, fmaf(x0.w, l3, dot0))));
        dot1 = fmaf(x1.x, l0, fmaf(x1.y, l1, fmaf(x1.z, l2, fmaf(x1.w, l3, dot1))));
        dot2 = fmaf(x2.x, l0, fmaf(x2.y, l1, fmaf(x2.z, l2, fmaf(x2.w, l3, dot2))));
        dot3 = fmaf(x3.x, l0, fmaf(x3.y, l1, fmaf(x3.z, l2, fmaf(x3.w, l3, dot3))));
    }

    const float y2 = ln2[m];
    float dots[4] = {dot0, dot1, dot2, dot3};
    #pragma unroll
    for (int r = 0; r < 4; ++r) {
        const float x2 = sx2[r];
        const float xy = -dots[r];
        const float a  = 1.0f + 2.0f * HYP_C * xy + HYP_C * y2;
        const float bb = 1.0f - HYP_C * x2;
        const float denom  = 1.0f + 2.0f * HYP_C * xy + HYP_C * HYP_C * x2 * y2;
        const float num_sq = a * a * x2 + 2.0f * a * bb * xy + bb * bb * y2;
        const float nrm = sqrtf(fmaxf(num_sq, 1e-12f)) / fabsf(denom + 1e-5f);
        float u = SQRT_C * nrm;
        u = fminf(fmaxf(u, -1.0f + 1e-5f), 1.0f - 1e-5f);
        const float d = (2.0f / SQRT_C) * (0.5f * (log1pf(u) - log1pf(-u)));
        Dout[(size_t)(row0 + r) * NPROX + m] = d;
    }
}

// ---------------------------------------------------------------------------
// Kernel C: fused ghhc. 256-thread blocks, 16 lanes per triplet (16 elems
// per lane), 4 triplets per wave-iteration, 4 iterations per wave.
// Zero DS ops and zero dependent loads in the loop:
//  - argmax: DPP row_ror rotate-reduce (fmax), then first-index walk in
//    registers, then DPP imin for exact jnp first-index tie-break
//  - epilogue d[A]/d[B] values extracted from registers during the walk and
//    broadcast via DPP fmax (distances >= 0, identity = -1)
// ---------------------------------------------------------------------------
__device__ __forceinline__ float dpp_fmax16(float x) {
    int o;
    o = __builtin_amdgcn_update_dpp(0, __float_as_int(x), 0x121, 0xF, 0xF, true);
    x = fmaxf(x, __int_as_float(o));
    o = __builtin_amdgcn_update_dpp(0, __float_as_int(x), 0x122, 0xF, 0xF, true);
    x = fmaxf(x, __int_as_float(o));
    o = __builtin_amdgcn_update_dpp(0, __float_as_int(x), 0x124, 0xF, 0xF, true);
    x = fmaxf(x, __int_as_float(o));
    o = __builtin_amdgcn_update_dpp(0, __float_as_int(x), 0x128, 0xF, 0xF, true);
    x = fmaxf(x, __int_as_float(o));
    return x;
}

__device__ __forceinline__ int dpp_imin16(int x) {
    int o;
    o = __builtin_amdgcn_update_dpp(0, x, 0x121, 0xF, 0xF, true); x = min(x, o);
    o = __builtin_amdgcn_update_dpp(0, x, 0x122, 0xF, 0xF, true); x = min(x, o);
    o = __builtin_amdgcn_update_dpp(0, x, 0x124, 0xF, 0xF, true); x = min(x, o);
    o = __builtin_amdgcn_update_dpp(0, x, 0x128, 0xF, 0xF, true); x = min(x, o);
    return x;
}

__global__ __launch_bounds__(256)
void ghhc_fused_kernel(const float* __restrict__ Da, const float* __restrict__ Db,
                       const float* __restrict__ Dc, const float* __restrict__ Dd,
                       const int* __restrict__ ta, const int* __restrict__ tb,
                       const int* __restrict__ tc, const int* __restrict__ td,
                       const float* __restrict__ ga, const float* __restrict__ gb,
                       const float* __restrict__ gc, const float* __restrict__ gd,
                       int Ta, int Tb, int Tc, int Td,
                       float sa, float sb, float sc_, float sd,
                       int nba, int nbb, int nbc,
                       float* __restrict__ out)
{
    const int tid = threadIdx.x;
    const int w   = tid >> 6;
    const int grp = (tid >> 4) & 3;
    const int hl  = tid & 15;
    const int hl4 = hl << 2;

    const int b = blockIdx.x;
    const float* D; const int* tr; const float* g; int Tt; float sc; int lb;
    if (b < nba)                   { D = Da; tr = ta; g = ga; Tt = Ta; sc = sa;  lb = b; }
    else if (b < nba + nbb)        { D = Db; tr = tb; g = gb; Tt = Tb; sc = sb;  lb = b - nba; }
    else if (b < nba + nbb + nbc)  { D = Dc; tr = tc; g = gc; Tt = Tc; sc = sc_; lb = b - nba - nbb; }
    else                           { D = Dd; tr = td; g = gd; Tt = Td; sc = sd;  lb = b - nba - nbb - nbc; }

    const int tstart = lb * 64 + w * 16;

    // prefetch triplet indices for all 4 iterations (independent loads)
    int iIt[4], jIt[4], kIt[4]; bool okIt[4];
    #pragma unroll
    for (int it = 0; it < 4; ++it) {
        int t = tstart + it * 4 + grp;
        okIt[it] = (t < Tt);
        t = okIt[it] ? t : (Tt - 1);
        iIt[it] = tr[t]; jIt[it] = tr[Tt + t]; kIt[it] = tr[2 * Tt + t];
    }

    float acc = 0.0f;

    #pragma unroll 1
    for (int it = 0; it < 4; ++it) {
        int t = tstart + it * 4 + grp;
        t = okIt[it] ? t : (Tt - 1);
        const int i = iIt[it], j = jIt[it], kk = kIt[it];

        const float4* Di = (const float4*)(D + (size_t)i  * NPROX);
        const float4* Dj = (const float4*)(D + (size_t)j  * NPROX);
        const float4* Dk = (const float4*)(D + (size_t)kk * NPROX);
        const float4* G0 = (const float4*)(g + (size_t)t * NPROX);
        const float4* G1 = (const float4*)(g + ((size_t)Tt + t) * NPROX);

        float dif[16], djf[16], dkf[16], g0f[16], g1f[16];
        #pragma unroll
        for (int m = 0; m < 4; ++m) {
            const int q = m * 16 + hl;
            float4 v;
            v = Di[q]; dif[m*4+0]=v.x; dif[m*4+1]=v.y; dif[m*4+2]=v.z; dif[m*4+3]=v.w;
            v = Dj[q]; djf[m*4+0]=v.x; djf[m*4+1]=v.y; djf[m*4+2]=v.z; djf[m*4+3]=v.w;
            v = Dk[q]; dkf[m*4+0]=v.x; dkf[m*4+1]=v.y; dkf[m*4+2]=v.z; dkf[m*4+3]=v.w;
            v = G0[q]; g0f[m*4+0]=v.x; g0f[m*4+1]=v.y; g0f[m*4+2]=v.z; g0f[m*4+3]=v.w;
            v = G1[q]; g1f[m*4+0]=v.x; g1f[m*4+1]=v.y; g1f[m*4+2]=v.z; g1f[m*4+3]=v.w;
        }

        float Sf[16], Uf[16];
        #pragma unroll
        for (int c = 0; c < 16; ++c) {
            const float m1 = fmaxf(dif[c], djf[c]);
            Sf[c] = fmaf(m1, -10.0f, g0f[c]);
            const float m2 = fmaxf(dkf[c], m1);
            Uf[c] = fmaf(m2, -10.0f, g1f[c]);
        }

        // phase 1: group max value
        float lvA = Sf[0], lvB = Uf[0];
        #pragma unroll
        for (int c = 1; c < 16; ++c) { lvA = fmaxf(lvA, Sf[c]); lvB = fmaxf(lvB, Uf[c]); }
        const float gvA = dpp_fmax16(lvA);
        const float gvB = dpp_fmax16(lvB);

        // phase 2: first matching slot in this lane + payloads (walk descending)
        int slA = 64, slB = 64;
        float pAi = -1.f, pAj = -1.f, pAk = -1.f;
        float pBi = -1.f, pBj = -1.f, pBk = -1.f;
        #pragma unroll
        for (int c = 15; c >= 0; --c) {
            const bool mA = (Sf[c] == gvA);
            slA = mA ? c : slA;
            pAi = mA ? dif[c] : pAi; pAj = mA ? djf[c] : pAj; pAk = mA ? dkf[c] : pAk;
            const bool mB = (Uf[c] == gvB);
            slB = mB ? c : slB;
            pBi = mB ? dif[c] : pBi; pBj = mB ? djf[c] : pBj; pBk = mB ? dkf[c] : pBk;
        }

        // slot -> global element index e = m*64 + hl*4 + c  (order-preserving)
        const int eA = (slA < 16) ? (((slA & 12) << 4) | (hl4 | (slA & 3))) : 1024;
        const int eB = (slB < 16) ? (((slB & 12) << 4) | (hl4 | (slB & 3))) : 1024;
        const int Ag = dpp_imin16(eA);
        const int Bg = dpp_imin16(eB);

        // broadcast owner's payloads to the group (d >= 0, identity -1)
        const bool ownA = (eA == Ag);
        const bool ownB = (eB == Bg);
        const float diA = dpp_fmax16(ownA ? pAi : -1.f);
        const float djA = dpp_fmax16(ownA ? pAj : -1.f);
        const float dkA = dpp_fmax16(ownA ? pAk : -1.f);
        const float diB = dpp_fmax16(ownB ? pBi : -1.f);
        const float djB = dpp_fmax16(ownB ? pBj : -1.f);
        const float dkB = dpp_fmax16(ownB ? pBk : -1.f);

        const float hc = fmaxf(diA - diB + MRG, 0.0f)
                       + fmaxf(djA - djB + MRG, 0.0f)
                       + fmaxf(dkB - dkA + MRG, 0.0f);
        acc += (okIt[it] && (Ag != Bg) && (hl == 0)) ? hc * sc : 0.0f;
    }

    // wave sum: nonzero only on lanes 0,16,32,48
    acc += __shfl_xor(acc, 16, 64);
    acc += __shfl_xor(acc, 32, 64);
    __shared__ float wsum[4];
    if ((tid & 63) == 0) wsum[w] = acc;
    __syncthreads();
    if (tid == 0)
        atomicAdd(out, wsum[0] + wsum[1] + wsum[2] + wsum[3]);
}

// ---------------------------------------------------------------------------
extern "C" void kernel_launch(void* const* d_in, const int* in_sizes, int n_in,
                              void* d_out, int out_size, void* d_ws, size_t ws_size,
                              hipStream_t stream)
{
    const float* z_s  = (const float*)d_in[0];
    const float* t_s  = (const float*)d_in[1];
    const float* lcas = (const float*)d_in[3];
    const int* trip1 = (const int*)d_in[4];
    const int* trip2 = (const int*)d_in[5];
    const int* trip3 = (const int*)d_in[6];
    const int* trip4 = (const int*)d_in[7];
    const float* g1 = (const float*)d_in[8];
    const float* g2 = (const float*)d_in[9];
    const float* g3 = (const float*)d_in[10];
    const float* g4 = (const float*)d_in[11];
    float* out = (float*)d_out;
    float* ws  = (float*)d_ws;

    const int T1 = in_sizes[4] / 3;   // 51200
    const int T2 = in_sizes[5] / 3;   // 12800
    const int T3 = in_sizes[6] / 3;   // 51200
    const int T4 = in_sizes[7] / 3;   // 12800
    const int BS = in_sizes[0] / DIM; // 1024
    const int nb1 = BS / 4;

    to_poincare_kernel<<<NPROX, 128, 0, stream>>>(lcas, ws, out);

    dist_all_kernel<<<2 * nb1 + 64, 256, 0, stream>>>(z_s, t_s, ws, nb1);

    // 64 triplets per block (4 waves x 4 groups x 4 iterations)
    const int nbA = (T1 + 63) / 64;   // 800
    const int nbB = (T2 + 63) / 64;   // 200
    const int nbC = (T3 + 63) / 64;   // 800
    const int nbD = (T4 + 63) / 64;   // 200
    ghhc_fused_kernel<<<nbA + nbB + nbC + nbD, 256, 0, stream>>>(
        ws + OFF_D1, ws + OFF_D2, ws + OFF_D3, ws + OFF_D2,
        trip1, trip2, trip3, trip4,
        g1, g2, g3, g4,
        T1, T2, T3, T4,
        1.0f / (float)T1, 1.0f / (float)T2, 1.0f / (float)T3, 1.0f / (float)T4,
        nbA, nbB, nbC,
        out);
}